// Round 13
// baseline (291.571 us; speedup 1.0000x reference)
//
#include <hip/hip_runtime.h>
#include <hip/hip_bf16.h>

#define F      128
#define NROWS  2048
#define MROWS  2048
#define BN     128         // n-rows per pair block
#define BM     64          // m-cols per pair block
#define MT     (MROWS/BM)  // 32 m-tiles
#define LOG2E  1.44269504088896340736f

// LDS: row-chunk = 16 data floats (8 p0 | 8 p1) + 4 pad = 20 floats (80 B)
// stride 80 ≡ 16 (mod 128): measured zero-conflict pattern (R10/R11)
#define ROWF   20
#define AB_F   (BN * ROWF)        // 2560
#define BB_F   (BM * ROWF)        // 1280
#define BUF_F  (AB_F + BB_F)      // 3840 floats / 15360 B per chunk-buffer
// 4 buffers: [group][dbuf]  -> 15360 floats; + w2l 128 -> 61952 B total
#define GRP_F  (2 * BUF_F)        // 7680

typedef float f32x4 __attribute__((ext_vector_type(4)));

__device__ __forceinline__ void gload16(const float* g, float* l) {
    __builtin_amdgcn_global_load_lds(
        (const __attribute__((address_space(1))) void*)g,
        (__attribute__((address_space(3))) void*)l, 16, 0, 0);
}

// --- Kernel 1: projections + ELU/w2 precompute + w2sum ----------------------
// a = (embeds@W1)[n][g], b = (base@W1)[m][g], w = w2[g]
// Global layout: P[row][ch][0..7]=plane0(g=ch*8+o), [8..15]=plane1 (256 f/row)
// PA: p0=(a+1)*w, p1=exp(a)*w ; PB: p0=-b*w, p1=exp(-b)
// w*elu(a-b) + w = med3(p0A + p0B, p1A * p1B, w)
__global__ __launch_bounds__(256) void proj_kernel(
    const float* __restrict__ embeds, const float* __restrict__ base,
    const float* __restrict__ W1, const float* __restrict__ w2,
    float* __restrict__ PA, float* __restrict__ PB,
    float* __restrict__ w2sum)
{
    const int tid = threadIdx.x;
    const int sub = tid >> 7;
    const int g   = tid & 127;
    const int row = blockIdx.x * 2 + sub;

    __shared__ float xs[2][F];
    {
        const float* src = (row < NROWS) ? &embeds[(size_t)row * F]
                                         : &base[(size_t)(row - NROWS) * F];
        xs[sub][g] = src[g];
    }
    __syncthreads();

    float acc = 0.0f;
#pragma unroll 8
    for (int f = 0; f < F; ++f)
        acc = fmaf(xs[sub][f], W1[f * F + g], acc);

    const float wv = w2[g];
    const int   ch = g >> 3, o = g & 7;
    if (row < NROWS) {
        float* dst = PA + (size_t)row * 256 + ch * 16 + o;
        dst[0] = (acc + 1.0f) * wv;
        dst[8] = __builtin_amdgcn_exp2f(acc * LOG2E) * wv;
    } else {
        float* dst = PB + (size_t)(row - NROWS) * 256 + ch * 16 + o;
        dst[0] = -acc * wv;
        dst[8] = __builtin_amdgcn_exp2f(-acc * LOG2E);
    }

    if (blockIdx.x == 0 && tid < 64) {
        float s = w2[tid] + w2[tid + 64];
#pragma unroll
        for (int k = 1; k < 64; k <<= 1) s += __shfl_xor(s, k);
        if (tid == 0) *w2sum = s;
    }
}

// --- Kernel 2: pair kernel -----------------------------------------------------
// grid (16,32), 512 threads = 2 wave-GROUPS of 256. Tile 128(n)x64(m), Rn=8,Rm=4.
// Group G computes g-chunks [8G, 8G+8) only (half the g range), with its own
// double-buffered LDS region + R10's padded-row staging. After the loop,
// group 1 deposits its 32 partial dots in LDS; group 0 combines and runs the
// epilogue. 2x waves/SIMD vs R11 at identical DS traffic.
__global__ __launch_bounds__(512, 4) void pair_kernel(
    const float* __restrict__ PA, const float* __restrict__ PB,
    const float* __restrict__ w2, const float* __restrict__ w2sum_p,
    const float* __restrict__ brew, float* __restrict__ partials)
{
    __shared__ float sbuf[4 * BUF_F];   // 61440 B ; combine area reuses this
    __shared__ float w2l[F];

    const int tid = threadIdx.x;
    const int G   = tid >> 8;            // wave-group 0/1
    const int tl  = tid & 255;           // thread within group
    const int wvi = tl >> 6, l = tid & 63;
    const int nt  = blockIdx.x, mt = blockIdx.y;
    const int n0  = nt * BN,    m0 = mt * BM;
    const int tr  = tl >> 4,    tc = tl & 15;
    const int gbase = G * GRP_F;

    // --- staging precompute (per group; R10 pattern): k = wvi+4t; k<10 A, else B
    const float* ssrc[4];
    int sdst[4];
#pragma unroll
    for (int t = 0; t < 4; ++t) {
        const int k = wvi + 4 * t;
        int slot, dstf;
        const float* basep;
        if (k < 10) { slot = 64 * k + l;        dstf = k * 256;               basep = PA + (size_t)n0 * 256; }
        else        { slot = 64 * (k - 10) + l; dstf = AB_F + (k - 10) * 256; basep = PB + (size_t)m0 * 256; }
        const int row = slot / 5;              // 5 x 16B slots per 80B LDS row
        int rs = slot - row * 5;               // 0..3 data, 4 = pad (re-fetch slot 0)
        if (rs == 4) rs = 0;
        ssrc[t] = basep + row * 256 + rs * 4;  // chunk stride = 16 floats
        sdst[t] = dstf;
    }
    const bool has3 = (wvi < 3);

#define STAGE(CH, BUF) {                                                       \
    float* db = &sbuf[gbase + (BUF) * BUF_F];                                  \
    gload16(ssrc[0] + (CH) * 16, db + sdst[0]);                                \
    gload16(ssrc[1] + (CH) * 16, db + sdst[1]);                                \
    gload16(ssrc[2] + (CH) * 16, db + sdst[2]);                                \
    if (has3) gload16(ssrc[3] + (CH) * 16, db + sdst[3]); }

    float acc[8][4];
#pragma unroll
    for (int i = 0; i < 8; ++i)
#pragma unroll
        for (int j = 0; j < 4; ++j) acc[i][j] = 0.0f;

    STAGE(8 * G, 0)
    if (tid < F) w2l[tid] = w2[tid];
    __syncthreads();

#pragma unroll 1
    for (int it = 0; it < 8; ++it) {
        const int ch  = 8 * G + it;
        const int buf = it & 1;
        if (it + 1 < 8) STAGE(ch + 1, buf ^ 1)

        const float* sa  = &sbuf[gbase + buf * BUF_F];
        const float* sbb = sa + AB_F;

#pragma unroll
        for (int h = 0; h < 2; ++h) {          // two 4-g halves of the 8-g chunk
            const float wq0 = w2l[ch * 8 + h * 4 + 0];
            const float wq1 = w2l[ch * 8 + h * 4 + 1];
            const float wq2 = w2l[ch * 8 + h * 4 + 2];
            const float wq3 = w2l[ch * 8 + h * 4 + 3];
            f32x4 b1v[4], bev[4];
#pragma unroll
            for (int j = 0; j < 4; ++j) {
                const float* bp = sbb + (tc + 16 * j) * ROWF + h * 4;
                b1v[j] = *(const f32x4*)bp;
                bev[j] = *(const f32x4*)(bp + 8);
            }
#pragma unroll
            for (int i = 0; i < 8; ++i) {
                const float* ap = sa + (tr + 16 * i) * ROWF + h * 4;
                const f32x4 a1 = *(const f32x4*)ap;
                const f32x4 ae = *(const f32x4*)(ap + 8);
#pragma unroll
                for (int j = 0; j < 4; ++j) {
                    const float s0 = __builtin_amdgcn_fmed3f(a1.x + b1v[j].x, ae.x * bev[j].x, wq0);
                    const float s1 = __builtin_amdgcn_fmed3f(a1.y + b1v[j].y, ae.y * bev[j].y, wq1);
                    const float s2 = __builtin_amdgcn_fmed3f(a1.z + b1v[j].z, ae.z * bev[j].z, wq2);
                    const float s3 = __builtin_amdgcn_fmed3f(a1.w + b1v[j].w, ae.w * bev[j].w, wq3);
                    acc[i][j] += (s0 + s1) + (s2 + s3);
                }
            }
        }
        __syncthreads();
    }
#undef STAGE

    // --- combine the two g-halves, then epilogue (group 0) ---------------------
    __syncthreads();                       // everyone done with sbuf as tiles
    if (G == 1) {
#pragma unroll
        for (int i = 0; i < 8; ++i)
            *(f32x4*)&sbuf[tl * 36 + i * 4] =
                (f32x4){acc[i][0], acc[i][1], acc[i][2], acc[i][3]};
    }
    __syncthreads();
    if (G == 0) {
        const float w2sum = *w2sum_p;
        float rsv[4];
#pragma unroll
        for (int j = 0; j < 4; ++j) rsv[j] = brew[m0 + tc + 16 * j];

#pragma unroll
        for (int i = 0; i < 8; ++i) {
            const f32x4 o = *(const f32x4*)&sbuf[tl * 36 + i * 4];
            float sw = 0.0f, swr = 0.0f;
#pragma unroll
            for (int j = 0; j < 4; ++j) {
                const float tot  = acc[i][j] + o[j];
                const float dist = fabsf(tot - w2sum);
                const float wgt  = 1.0f / (dist + 1e-4f);
                sw += wgt;
                swr = fmaf(wgt, rsv[j], swr);
            }
#pragma unroll
            for (int k = 1; k < 16; k <<= 1) {
                sw  += __shfl_xor(sw, k);
                swr += __shfl_xor(swr, k);
            }
            if (tc == 0) {
                const int n = n0 + tr + 16 * i;
                partials[((size_t)n * MT + mt) * 2 + 0] = sw;
                partials[((size_t)n * MT + mt) * 2 + 1] = swr;
            }
        }
    }
}

// --- Kernel 3: reduce tile partials, divide ------------------------------------
__global__ __launch_bounds__(256) void finalize_kernel(
    const float* __restrict__ partials, float* __restrict__ out)
{
    const int n = blockIdx.x * 256 + threadIdx.x;
    if (n < NROWS) {
        float sw = 0.0f, swr = 0.0f;
#pragma unroll
        for (int t = 0; t < MT; ++t) {
            sw  += partials[((size_t)n * MT + t) * 2 + 0];
            swr += partials[((size_t)n * MT + t) * 2 + 1];
        }
        out[n] = swr / sw;
    }
}

extern "C" void kernel_launch(void* const* d_in, const int* in_sizes, int n_in,
                              void* d_out, int out_size, void* d_ws, size_t ws_size,
                              hipStream_t stream)
{
    const float* embeds       = (const float*)d_in[0];  // [2048,128]
    const float* base_embeds  = (const float*)d_in[1];  // [2048,128]
    const float* base_rewards = (const float*)d_in[2];  // [2048]
    const float* W1           = (const float*)d_in[3];  // [128,128] (in,out)
    const float* w2           = (const float*)d_in[4];  // [128,1]
    float* out = (float*)d_out;

    // ws: partials [2048*MT*2] | PA [2048*256] | PB [2048*256] | w2sum[1]
    float* partials = (float*)d_ws;
    float* PA  = partials + (size_t)NROWS * MT * 2;
    float* PB  = PA + (size_t)NROWS * 256;
    float* w2s = PB + (size_t)MROWS * 256;

    proj_kernel<<<(NROWS + MROWS) / 2, 256, 0, stream>>>(
        embeds, base_embeds, W1, w2, PA, PB, w2s);

    dim3 grid2(NROWS / BN, MROWS / BM);
    pair_kernel<<<grid2, 512, 0, stream>>>(PA, PB, w2, w2s, base_rewards, partials);

    finalize_kernel<<<(NROWS + 255) / 256, 256, 0, stream>>>(partials, out);
}

// Round 14
// 83.595 us; speedup vs baseline: 3.4879x; 3.4879x over previous
//
#include <hip/hip_runtime.h>
#include <hip/hip_bf16.h>

#define F      128
#define NROWS  2048
#define MROWS  2048
#define MT     32          // m-tiles of 64
#define LOG2E  1.44269504088896340736f

typedef float f32x4 __attribute__((ext_vector_type(4)));

// --- Kernel 1: projections + ELU/w2 precompute + w2sum ----------------------
// a = (embeds@W1)[n][g], b = (base@W1)[m][g], w = w2[g]
// PA row-chunk layout: PA[row][ch*16 + 0..7]=p0=(a+1)w, [8..15]=p1=exp(a)w
// BT4 transposed B layout: 64 rows of 2048 m x 4 floats:
//   BT4[(ch*4+q)][m][e], f=q*4+e: f 0..7 = p0=-b*w (g=f), f 8..15 = p1=exp(-b) (g=f-8)
// w*elu(a-b) + w = med3(p0A + p0B, p1A * p1B, w)  [median commutes with *w, any sign]
__global__ __launch_bounds__(256) void proj_kernel(
    const float* __restrict__ embeds, const float* __restrict__ base,
    const float* __restrict__ W1, const float* __restrict__ w2,
    float* __restrict__ PA, float* __restrict__ BT4,
    float* __restrict__ w2sum)
{
    const int tid = threadIdx.x;
    const int sub = tid >> 7;
    const int g   = tid & 127;
    const int row = blockIdx.x * 2 + sub;

    __shared__ float xs[2][F];
    {
        const float* src = (row < NROWS) ? &embeds[(size_t)row * F]
                                         : &base[(size_t)(row - NROWS) * F];
        xs[sub][g] = src[g];
    }
    __syncthreads();

    float acc = 0.0f;
#pragma unroll 8
    for (int f = 0; f < F; ++f)
        acc = fmaf(xs[sub][f], W1[f * F + g], acc);

    const float wv = w2[g];
    const int   ch = g >> 3, o = g & 7;
    if (row < NROWS) {
        float* dst = PA + (size_t)row * 256 + ch * 16 + o;
        dst[0] = (acc + 1.0f) * wv;
        dst[8] = __builtin_amdgcn_exp2f(acc * LOG2E) * wv;
    } else {
        const int m  = row - NROWS;
        const int f0 = o, f1 = 8 + o;
        BT4[((size_t)(ch * 4 + (f0 >> 2)) * 2048 + m) * 4 + (f0 & 3)] = -acc * wv;
        BT4[((size_t)(ch * 4 + (f1 >> 2)) * 2048 + m) * 4 + (f1 & 3)] =
            __builtin_amdgcn_exp2f(-acc * LOG2E);
    }

    if (blockIdx.x == 0 && tid < 64) {
        float s = w2[tid] + w2[tid + 64];
#pragma unroll
        for (int k = 1; k < 64; k <<= 1) s += __shfl_xor(s, k);
        if (tid == 0) *w2sum = s;
    }
}

// --- Kernel 2: pair kernel -----------------------------------------------------
// grid (64,32), 256 threads = 4 waves. Wave handles 8 n-rows x 64 m (lane = m).
// A data is wave-uniform -> scalar loads (SGPR operands); B read per-lane from
// BT4 (lane-coalesced dwordx4, reg double-buffered). NO LDS, NO barriers.
// Per elem-g: v_add(s,v) + v_mul(s,v) + v_med3(v,v,s) + acc-add = 4 VALU.
__global__ __launch_bounds__(256, 4) void pair_kernel(
    const float* __restrict__ PA, const float* __restrict__ BT4,
    const float* __restrict__ w2, const float* __restrict__ w2sum_p,
    const float* __restrict__ brew, float* __restrict__ partials)
{
    const int lane = threadIdx.x & 63;
    const int wv   = __builtin_amdgcn_readfirstlane(threadIdx.x >> 6);
    const int nt   = blockIdx.x, mt = blockIdx.y;
    const int n0   = nt * 32 + wv * 8;     // wave's first n-row (uniform)
    const int m0   = mt * 64;

    const float* bbase = BT4 + (size_t)(m0 + lane) * 4;   // per-lane B column

    float acc[8];
#pragma unroll
    for (int r = 0; r < 8; ++r) acc[r] = 0.0f;

    f32x4 rB[4], rBn[4];
#pragma unroll
    for (int q = 0; q < 4; ++q)
        rB[q] = *(const f32x4*)&bbase[(size_t)q * 8192];

#pragma unroll 1
    for (int ch = 0; ch < 16; ++ch) {
        if (ch < 15) {
#pragma unroll
            for (int q = 0; q < 4; ++q)
                rBn[q] = *(const f32x4*)&bbase[(size_t)((ch + 1) * 4 + q) * 8192];
        }
        const float* w2c = w2 + ch * 8;    // uniform -> scalar loads
        const float w0 = w2c[0], w1 = w2c[1], w2_ = w2c[2], w3 = w2c[3];
        const float w4 = w2c[4], w5 = w2c[5], w6 = w2c[6], w7 = w2c[7];

#pragma unroll
        for (int r = 0; r < 8; ++r) {
            const float* ar = PA + (size_t)(n0 + r) * 256 + ch * 16;  // uniform
            const f32x4 a10 = *(const f32x4*)&ar[0];   // p0 g0..3
            const f32x4 a11 = *(const f32x4*)&ar[4];   // p0 g4..7
            const f32x4 ae0 = *(const f32x4*)&ar[8];   // p1 g0..3
            const f32x4 ae1 = *(const f32x4*)&ar[12];  // p1 g4..7

            const float s0 = __builtin_amdgcn_fmed3f(a10[0] + rB[0][0], ae0[0] * rB[2][0], w0);
            const float s1 = __builtin_amdgcn_fmed3f(a10[1] + rB[0][1], ae0[1] * rB[2][1], w1);
            const float s2 = __builtin_amdgcn_fmed3f(a10[2] + rB[0][2], ae0[2] * rB[2][2], w2_);
            const float s3 = __builtin_amdgcn_fmed3f(a10[3] + rB[0][3], ae0[3] * rB[2][3], w3);
            const float s4 = __builtin_amdgcn_fmed3f(a11[0] + rB[1][0], ae1[0] * rB[3][0], w4);
            const float s5 = __builtin_amdgcn_fmed3f(a11[1] + rB[1][1], ae1[1] * rB[3][1], w5);
            const float s6 = __builtin_amdgcn_fmed3f(a11[2] + rB[1][2], ae1[2] * rB[3][2], w6);
            const float s7 = __builtin_amdgcn_fmed3f(a11[3] + rB[1][3], ae1[3] * rB[3][3], w7);
            acc[r] += ((s0 + s1) + (s2 + s3)) + ((s4 + s5) + (s6 + s7));
        }
#pragma unroll
        for (int q = 0; q < 4; ++q) rB[q] = rBn[q];
    }

    // --- epilogue: per-row inverse-distance, reduce over 64 m-lanes -------------
    const float w2sum = *w2sum_p;
    const float rv    = brew[m0 + lane];

#pragma unroll
    for (int r = 0; r < 8; ++r) {
        const float dist = fabsf(acc[r] - w2sum);
        const float wgt  = 1.0f / (dist + 1e-4f);
        float sw  = wgt;
        float swr = wgt * rv;
#pragma unroll
        for (int k = 1; k < 64; k <<= 1) {
            sw  += __shfl_xor(sw, k);
            swr += __shfl_xor(swr, k);
        }
        if (lane == 0) {
            const int n = n0 + r;
            partials[((size_t)n * MT + mt) * 2 + 0] = sw;
            partials[((size_t)n * MT + mt) * 2 + 1] = swr;
        }
    }
}

// --- Kernel 3: reduce tile partials, divide ------------------------------------
__global__ __launch_bounds__(256) void finalize_kernel(
    const float* __restrict__ partials, float* __restrict__ out)
{
    const int n = blockIdx.x * 256 + threadIdx.x;
    if (n < NROWS) {
        float sw = 0.0f, swr = 0.0f;
#pragma unroll
        for (int t = 0; t < MT; ++t) {
            sw  += partials[((size_t)n * MT + t) * 2 + 0];
            swr += partials[((size_t)n * MT + t) * 2 + 1];
        }
        out[n] = swr / sw;
    }
}

extern "C" void kernel_launch(void* const* d_in, const int* in_sizes, int n_in,
                              void* d_out, int out_size, void* d_ws, size_t ws_size,
                              hipStream_t stream)
{
    const float* embeds       = (const float*)d_in[0];  // [2048,128]
    const float* base_embeds  = (const float*)d_in[1];  // [2048,128]
    const float* base_rewards = (const float*)d_in[2];  // [2048]
    const float* W1           = (const float*)d_in[3];  // [128,128] (in,out)
    const float* w2           = (const float*)d_in[4];  // [128,1]
    float* out = (float*)d_out;

    // ws: partials [2048*MT*2] | PA [2048*256] | BT4 [64*2048*4] | w2sum[1]
    float* partials = (float*)d_ws;
    float* PA  = partials + (size_t)NROWS * MT * 2;
    float* BT4 = PA + (size_t)NROWS * 256;
    float* w2s = BT4 + (size_t)64 * 2048 * 4;

    proj_kernel<<<(NROWS + MROWS) / 2, 256, 0, stream>>>(
        embeds, base_embeds, W1, w2, PA, BT4, w2s);

    dim3 grid2(NROWS / 32, MROWS / 64);
    pair_kernel<<<grid2, 256, 0, stream>>>(PA, BT4, w2, w2s, base_rewards, partials);

    finalize_kernel<<<(NROWS + 255) / 256, 256, 0, stream>>>(partials, out);
}